// Round 1
// baseline (5022.585 us; speedup 1.0000x reference)
//
#include <hip/hip_runtime.h>
#include <math.h>

#define LRELU(x) ((x) > 0.0f ? (x) : 0.2f * (x))

__device__ __forceinline__ void atomicMaxFloat(float* addr, float val) {
    if (val >= 0.0f) atomicMax((int*)addr, __float_as_int(val));
    else             atomicMin((unsigned int*)addr, __float_as_uint(val));
}

// ---------------- GEMM: C[M,N] = A[M,K] @ B[K,N], fp32, row-major ----------------
template <int BM, int BN, int BK, int TM, int TN>
__global__ __launch_bounds__(256) void sgemm_kernel(
    const float* __restrict__ A, const float* __restrict__ B, float* __restrict__ C,
    int M, int N, int K)
{
    __shared__ float As[BK][BM + 1];
    __shared__ float Bs[BK][BN + 1];
    const int tid = threadIdx.x;
    const int tx = tid % (BN / TN);
    const int ty = tid / (BN / TN);
    const int row0 = blockIdx.x * BM;
    const int col0 = blockIdx.y * BN;

    float acc[TM][TN] = {};
    for (int k0 = 0; k0 < K; k0 += BK) {
        for (int e = tid; e < BM * BK; e += 256) {
            int m = e / BK, k = e % BK;
            As[k][m] = (row0 + m < M) ? A[(size_t)(row0 + m) * K + k0 + k] : 0.0f;
        }
        for (int e = tid; e < BK * BN; e += 256) {
            int k = e / BN, n = e % BN;
            Bs[k][n] = B[(size_t)(k0 + k) * N + col0 + n];
        }
        __syncthreads();
#pragma unroll
        for (int k = 0; k < BK; ++k) {
            float a[TM], b[TN];
#pragma unroll
            for (int i = 0; i < TM; ++i) a[i] = As[k][ty * TM + i];
#pragma unroll
            for (int j = 0; j < TN; ++j) b[j] = Bs[k][tx * TN + j];
#pragma unroll
            for (int i = 0; i < TM; ++i)
#pragma unroll
                for (int j = 0; j < TN; ++j) acc[i][j] += a[i] * b[j];
        }
        __syncthreads();
    }
#pragma unroll
    for (int i = 0; i < TM; ++i) {
        int r = row0 + ty * TM + i;
        if (r >= M) continue;
#pragma unroll
        for (int j = 0; j < TN; ++j)
            C[(size_t)r * N + col0 + tx * TN + j] = acc[i][j];
    }
}

// --------- attention coefficients: as[n,h] = <h[n,h,:], att_src[h,:]> (ditto ad) ---------
__global__ __launch_bounds__(256) void attn_coef_kernel(
    const float* __restrict__ h, const float* __restrict__ att_src,
    const float* __restrict__ att_dst, float* __restrict__ as_, float* __restrict__ ad_,
    int N, int H, int C)
{
    int idx = blockIdx.x * blockDim.x + threadIdx.x;  // n*H + h
    if (idx >= N * H) return;
    int hh = idx % H;
    const float* hp  = h + (size_t)idx * C;
    const float* asv = att_src + hh * C;
    const float* adv = att_dst + hh * C;
    float s = 0.0f, d = 0.0f;
    for (int c = 0; c < C; ++c) { float v = hp[c]; s += v * asv[c]; d += v * adv[c]; }
    as_[idx] = s;
    ad_[idx] = d;
}

// --------- init m/denom/out (ws is re-poisoned to 0xAA before every call) ---------
__global__ __launch_bounds__(256) void init_kernel(
    float* __restrict__ m, float* __restrict__ denom, float* __restrict__ out,
    int NH, int NHC)
{
    int i = blockIdx.x * blockDim.x + threadIdx.x;
    int stride = gridDim.x * blockDim.x;
    for (int j = i; j < NH; j += stride) { m[j] = -1e30f; denom[j] = 0.0f; }
    for (int j = i; j < NHC; j += stride) out[j] = 0.0f;
}

// --------- segment max of leaky_relu(as[src]+ad[dst]) over dst ---------
__global__ __launch_bounds__(256) void edge_max_kernel(
    const int* __restrict__ ei, int E, int N, int H,
    const float* __restrict__ as_, const float* __restrict__ ad_, float* __restrict__ m)
{
    int k = blockIdx.x * blockDim.x + threadIdx.x;
    int Et = E + N;
    if (k >= Et) return;
    int src, dst;
    if (k < E) { src = ei[k]; dst = ei[E + k]; }
    else       { src = dst = k - E; }
    for (int hh = 0; hh < H; ++hh) {
        float e = as_[src * H + hh] + ad_[dst * H + hh];
        e = LRELU(e);
        atomicMaxFloat(&m[dst * H + hh], e);
    }
}

// --------- ex = exp(e - m[dst]); accumulate denom; stash ex per edge ---------
__global__ __launch_bounds__(256) void edge_exp_kernel(
    const int* __restrict__ ei, int E, int N, int H,
    const float* __restrict__ as_, const float* __restrict__ ad_,
    const float* __restrict__ m, float* __restrict__ ex_buf, float* __restrict__ denom)
{
    int k = blockIdx.x * blockDim.x + threadIdx.x;
    int Et = E + N;
    if (k >= Et) return;
    int src, dst;
    if (k < E) { src = ei[k]; dst = ei[E + k]; }
    else       { src = dst = k - E; }
    for (int hh = 0; hh < H; ++hh) {
        float e = as_[src * H + hh] + ad_[dst * H + hh];
        e = LRELU(e);
        float ex = __expf(e - m[dst * H + hh]);
        ex_buf[k * H + hh] = ex;
        atomicAdd(&denom[dst * H + hh], ex);
    }
}

// --------- scatter aggregation: out[dst,h,c] += ex * h[src,h,c] (float4 per thread) ---------
template <int H, int C>
__global__ __launch_bounds__(256) void edge_aggr_kernel(
    const int* __restrict__ ei, int E, int N,
    const float* __restrict__ ex_buf, const float* __restrict__ h, float* __restrict__ out)
{
    constexpr int HC  = H * C;
    constexpr int HC4 = HC / 4;         // float4 slots per edge
    constexpr int EPB = 256 / HC4;      // edges per block
    int k = blockIdx.x * EPB + threadIdx.x / HC4;
    int q = threadIdx.x % HC4;
    int Et = E + N;
    if (k >= Et) return;
    int src, dst;
    if (k < E) { src = ei[k]; dst = ei[E + k]; }
    else       { src = dst = k - E; }
    int c4 = q * 4;
    int hh = c4 / C;
    float ex = ex_buf[k * H + hh];
    const float4 hv = *(const float4*)(h + (size_t)src * HC + c4);
    float* op = out + (size_t)dst * HC + c4;
    atomicAdd(op + 0, ex * hv.x);
    atomicAdd(op + 1, ex * hv.y);
    atomicAdd(op + 2, ex * hv.z);
    atomicAdd(op + 3, ex * hv.w);
}

// --------- finalize layer 1 (in-place): x = lrelu(x/denom + bias) ---------
__global__ __launch_bounds__(256) void finalize1_kernel(
    float* __restrict__ x, const float* __restrict__ denom, const float* __restrict__ bias,
    int N, int H, int C)
{
    int idx = blockIdx.x * blockDim.x + threadIdx.x;
    if (idx >= N * H * C) return;
    int n = idx / (H * C);
    int c = idx % (H * C);
    int hh = c / C;
    float v = x[idx] / denom[n * H + hh] + bias[c];
    x[idx] = LRELU(v);
}

// --------- finalize layer 2: out = lrelu(aggr/denom + bias) + features ---------
__global__ __launch_bounds__(256) void finalize2_kernel(
    const float* __restrict__ aggr, const float* __restrict__ denom,
    const float* __restrict__ bias, const float* __restrict__ feat,
    float* __restrict__ outp, int N, int C)
{
    int idx = blockIdx.x * blockDim.x + threadIdx.x;
    if (idx >= N * C) return;
    int n = idx / C;
    int c = idx % C;
    float v = aggr[idx] / denom[n] + bias[c];
    outp[idx] = LRELU(v) + feat[idx];
}

extern "C" void kernel_launch(void* const* d_in, const int* in_sizes, int n_in,
                              void* d_out, int out_size, void* d_ws, size_t ws_size,
                              hipStream_t stream)
{
    const float* feat = (const float*)d_in[0];
    const int*   ei   = (const int*)d_in[1];
    const float* W1   = (const float*)d_in[2];
    const float* asrc1 = (const float*)d_in[3];
    const float* adst1 = (const float*)d_in[4];
    const float* bias1 = (const float*)d_in[5];
    const float* W2    = (const float*)d_in[6];
    const float* asrc2 = (const float*)d_in[7];
    const float* adst2 = (const float*)d_in[8];
    const float* bias2 = (const float*)d_in[9];
    float* outp = (float*)d_out;

    const int IN_DIM = 128, H1 = 4, C1 = 64, HC1 = 256, C2 = 128;
    const int N = in_sizes[0] / IN_DIM;
    const int E = in_sizes[1] / 2;
    const int Et = E + N;

    // workspace layout (floats)
    float* ws  = (float*)d_ws;
    float* h1  = ws;                         // N*256
    float* x1  = h1 + (size_t)N * HC1;       // N*256 (layer-1 output / layer-2 input)
    float* h2  = x1 + (size_t)N * HC1;       // N*128
    float* ex  = h2 + (size_t)N * C2;        // Et*4 (layer1); layer2 reuses (Et*1)
    float* as_ = ex + (size_t)Et * 4;        // N*4
    float* ad_ = as_ + (size_t)N * 4;        // N*4
    float* mb  = ad_ + (size_t)N * 4;        // N*4
    float* den = mb + (size_t)N * 4;         // N*4
    float* out2 = h1;                        // alias: h1 dead after layer-1 aggregation

    dim3 blk(256);

    // ================= layer 1 (H=4, C=64) =================
    {
        dim3 g1((N + 63) / 64, HC1 / 64);
        sgemm_kernel<64, 64, 16, 4, 4><<<g1, blk, 0, stream>>>(feat, W1, h1, N, HC1, IN_DIM);

        attn_coef_kernel<<<dim3((N * H1 + 255) / 256), blk, 0, stream>>>(h1, asrc1, adst1, as_, ad_, N, H1, C1);

        init_kernel<<<dim3(2048), blk, 0, stream>>>(mb, den, x1, N * H1, N * HC1);

        dim3 ge((Et + 255) / 256);
        edge_max_kernel<<<ge, blk, 0, stream>>>(ei, E, N, H1, as_, ad_, mb);
        edge_exp_kernel<<<ge, blk, 0, stream>>>(ei, E, N, H1, as_, ad_, mb, ex, den);

        edge_aggr_kernel<4, 64><<<dim3((Et + 3) / 4), blk, 0, stream>>>(ei, E, N, ex, h1, x1);

        finalize1_kernel<<<dim3((N * HC1 + 255) / 256), blk, 0, stream>>>(x1, den, bias1, N, H1, C1);
    }

    // ================= layer 2 (H=1, C=128) =================
    {
        dim3 g2((N + 63) / 64, C2 / 64);
        sgemm_kernel<64, 64, 16, 4, 4><<<g2, blk, 0, stream>>>(x1, W2, h2, N, C2, HC1);

        attn_coef_kernel<<<dim3((N + 255) / 256), blk, 0, stream>>>(h2, asrc2, adst2, as_, ad_, N, 1, C2);

        init_kernel<<<dim3(2048), blk, 0, stream>>>(mb, den, out2, N, N * C2);

        dim3 ge((Et + 255) / 256);
        edge_max_kernel<<<ge, blk, 0, stream>>>(ei, E, N, 1, as_, ad_, mb);
        edge_exp_kernel<<<ge, blk, 0, stream>>>(ei, E, N, 1, as_, ad_, mb, ex, den);

        edge_aggr_kernel<1, 128><<<dim3((Et + 7) / 8), blk, 0, stream>>>(ei, E, N, ex, h2, out2);

        finalize2_kernel<<<dim3((N * C2 + 255) / 256), blk, 0, stream>>>(out2, den, bias2, feat, outp, N, C2);
    }
}

// Round 2
// 690.758 us; speedup vs baseline: 7.2711x; 7.2711x over previous
//
#include <hip/hip_runtime.h>
#include <math.h>

#define LRELU(x) ((x) > 0.0f ? (x) : 0.2f * (x))

// ---------------- GEMM: C[M,N] = A[M,K] @ B[K,N], fp32, row-major ----------------
template <int BM, int BN, int BK, int TM, int TN>
__global__ __launch_bounds__(256) void sgemm_kernel(
    const float* __restrict__ A, const float* __restrict__ B, float* __restrict__ C,
    int M, int N, int K)
{
    __shared__ float As[BK][BM + 1];
    __shared__ float Bs[BK][BN + 1];
    const int tid = threadIdx.x;
    const int tx = tid % (BN / TN);
    const int ty = tid / (BN / TN);
    const int row0 = blockIdx.x * BM;
    const int col0 = blockIdx.y * BN;

    float acc[TM][TN] = {};
    for (int k0 = 0; k0 < K; k0 += BK) {
        for (int e = tid; e < BM * BK; e += 256) {
            int m = e / BK, k = e % BK;
            As[k][m] = (row0 + m < M) ? A[(size_t)(row0 + m) * K + k0 + k] : 0.0f;
        }
        for (int e = tid; e < BK * BN; e += 256) {
            int k = e / BN, n = e % BN;
            Bs[k][n] = B[(size_t)(k0 + k) * N + col0 + n];
        }
        __syncthreads();
#pragma unroll
        for (int k = 0; k < BK; ++k) {
            float a[TM], b[TN];
#pragma unroll
            for (int i = 0; i < TM; ++i) a[i] = As[k][ty * TM + i];
#pragma unroll
            for (int j = 0; j < TN; ++j) b[j] = Bs[k][tx * TN + j];
#pragma unroll
            for (int i = 0; i < TM; ++i)
#pragma unroll
                for (int j = 0; j < TN; ++j) acc[i][j] += a[i] * b[j];
        }
        __syncthreads();
    }
#pragma unroll
    for (int i = 0; i < TM; ++i) {
        int r = row0 + ty * TM + i;
        if (r >= M) continue;
#pragma unroll
        for (int j = 0; j < TN; ++j)
            C[(size_t)r * N + col0 + tx * TN + j] = acc[i][j];
    }
}

// --------- attention coefficients: as[n,h] = <h[n,h,:], att_src[h,:]> (ditto ad) ---------
__global__ __launch_bounds__(256) void attn_coef_kernel(
    const float* __restrict__ h, const float* __restrict__ att_src,
    const float* __restrict__ att_dst, float* __restrict__ as_, float* __restrict__ ad_,
    int N, int H, int C)
{
    int idx = blockIdx.x * blockDim.x + threadIdx.x;  // n*H + h
    if (idx >= N * H) return;
    int hh = idx % H;
    const float* hp  = h + (size_t)idx * C;
    const float* asv = att_src + hh * C;
    const float* adv = att_dst + hh * C;
    float s = 0.0f, d = 0.0f;
    for (int c = 0; c < C; ++c) { float v = hp[c]; s += v * asv[c]; d += v * adv[c]; }
    as_[idx] = s;
    ad_[idx] = d;
}

// ================= CSR build (done once per call; graph shared by both layers) =================
__global__ __launch_bounds__(256) void zero2_kernel(int* __restrict__ a, int* __restrict__ b, int N)
{
    int i = blockIdx.x * blockDim.x + threadIdx.x;
    int stride = gridDim.x * blockDim.x;
    for (int j = i; j < N; j += stride) { a[j] = 0; b[j] = 0; }
}

__global__ __launch_bounds__(256) void deg_kernel(
    const int* __restrict__ ei, int E, int N, int* __restrict__ deg)
{
    int k = blockIdx.x * blockDim.x + threadIdx.x;
    int Et = E + N;
    if (k >= Et) return;
    int dst = (k < E) ? ei[E + k] : (k - E);
    atomicAdd(&deg[dst], 1);
}

// per-block inclusive scan (256 elems), emits block sums
__global__ __launch_bounds__(256) void scan1_kernel(
    const int* __restrict__ deg, int* __restrict__ incl, int* __restrict__ bsum, int N)
{
    __shared__ int s[256];
    int t = threadIdx.x;
    int i = blockIdx.x * 256 + t;
    s[t] = (i < N) ? deg[i] : 0;
    __syncthreads();
    for (int off = 1; off < 256; off <<= 1) {
        int x = (t >= off) ? s[t - off] : 0;
        __syncthreads();
        s[t] += x;
        __syncthreads();
    }
    if (i < N) incl[i] = s[t];
    if (t == 255) bsum[blockIdx.x] = s[255];
}

// single-block inclusive scan of the block sums (nb <= 256)
__global__ __launch_bounds__(256) void scan2_kernel(int* __restrict__ bsum, int nb)
{
    __shared__ int s[256];
    int t = threadIdx.x;
    s[t] = (t < nb) ? bsum[t] : 0;
    __syncthreads();
    for (int off = 1; off < 256; off <<= 1) {
        int x = (t >= off) ? s[t - off] : 0;
        __syncthreads();
        s[t] += x;
        __syncthreads();
    }
    if (t < nb) bsum[t] = s[t];
}

__global__ __launch_bounds__(256) void scan3_kernel(
    const int* __restrict__ incl, const int* __restrict__ deg,
    const int* __restrict__ bsum, int* __restrict__ row_start, int N)
{
    int i = blockIdx.x * 256 + threadIdx.x;
    if (i >= N) return;
    int off = (blockIdx.x > 0) ? bsum[blockIdx.x - 1] : 0;
    row_start[i] = off + incl[i] - deg[i];   // exclusive scan
}

__global__ __launch_bounds__(256) void fill_kernel(
    const int* __restrict__ ei, int E, int N,
    const int* __restrict__ row_start, int* __restrict__ cursor, int* __restrict__ col)
{
    int k = blockIdx.x * blockDim.x + threadIdx.x;
    int Et = E + N;
    if (k >= Et) return;
    int src, dst;
    if (k < E) { src = ei[k]; dst = ei[E + k]; }
    else       { src = dst = k - E; }
    int pos = row_start[dst] + atomicAdd(&cursor[dst], 1);
    col[pos] = src;
}

// ================= fused per-dst gather: softmax + aggregation + epilogue =================
// one block per dst node, H*C threads; thread t owns output channel t (head t/C)
template <int H, int C, bool RES>
__global__ __launch_bounds__(H * C) void gat_gather_kernel(
    const int* __restrict__ row_start, const int* __restrict__ deg,
    const int* __restrict__ col,
    const float* __restrict__ as_, const float* __restrict__ ad_,
    const float* __restrict__ h, const float* __restrict__ bias,
    const float* __restrict__ resid, float* __restrict__ out, int N)
{
    constexpr int HC = H * C;
    constexpr int JT = HC / H;    // edge-parallel lanes per head
    constexpr int TILE = 32;
    __shared__ float red[HC];
    __shared__ float smax[H], sden[H], sad[H];
    __shared__ float salpha[TILE * H];
    __shared__ int   ssrc[TILE];

    const int n = blockIdx.x;
    const int t = threadIdx.x;
    const int start = row_start[n];
    const int dg = deg[n];

    if (t < H) sad[t] = ad_[n * H + t];
    __syncthreads();

    const int hh = t % H;      // head for edge-parallel phases
    const int j0 = t / H;
    const float adv = sad[hh];

    // ---- pass 1: per-head max of leaky_relu(as[src]+ad[n]) ----
    float lmax = -1e30f;
    for (int j = j0; j < dg; j += JT) {
        int src = col[start + j];
        float e = as_[src * H + hh] + adv;
        e = LRELU(e);
        lmax = fmaxf(lmax, e);
    }
    red[t] = lmax;
    __syncthreads();
    for (int s = HC / 2; s >= H; s >>= 1) {
        if (t < s) red[t] = fmaxf(red[t], red[t + s]);
        __syncthreads();
    }
    if (t < H) smax[t] = red[t];
    __syncthreads();

    // ---- pass 2: per-head sum of exp ----
    const float mh = smax[hh];
    float lsum = 0.0f;
    for (int j = j0; j < dg; j += JT) {
        int src = col[start + j];
        float e = as_[src * H + hh] + adv;
        e = LRELU(e);
        lsum += __expf(e - mh);
    }
    red[t] = lsum;
    __syncthreads();
    for (int s = HC / 2; s >= H; s >>= 1) {
        if (t < s) red[t] += red[t + s];
        __syncthreads();
    }
    if (t < H) sden[t] = 1.0f / red[t];
    __syncthreads();

    // ---- pass 3: aggregate alpha * h[src] in edge tiles ----
    const int ch_head = t / C;
    float acc = 0.0f;
    for (int base = 0; base < dg; base += TILE) {
        int cnt = min(TILE, dg - base);
        for (int idx = t; idx < cnt * H; idx += HC) {
            int j = idx / H, h2 = idx % H;
            int src = col[start + base + j];
            if (h2 == 0) ssrc[j] = src;
            float e = as_[src * H + h2] + sad[h2];
            e = LRELU(e);
            salpha[idx] = __expf(e - smax[h2]) * sden[h2];
        }
        __syncthreads();
        for (int j = 0; j < cnt; ++j)
            acc += salpha[j * H + ch_head] * h[(size_t)ssrc[j] * HC + t];
        __syncthreads();
    }

    float v = acc + bias[t];
    v = LRELU(v);
    if (RES) v += resid[(size_t)n * HC + t];
    out[(size_t)n * HC + t] = v;
}

extern "C" void kernel_launch(void* const* d_in, const int* in_sizes, int n_in,
                              void* d_out, int out_size, void* d_ws, size_t ws_size,
                              hipStream_t stream)
{
    const float* feat = (const float*)d_in[0];
    const int*   ei   = (const int*)d_in[1];
    const float* W1   = (const float*)d_in[2];
    const float* asrc1 = (const float*)d_in[3];
    const float* adst1 = (const float*)d_in[4];
    const float* bias1 = (const float*)d_in[5];
    const float* W2    = (const float*)d_in[6];
    const float* asrc2 = (const float*)d_in[7];
    const float* adst2 = (const float*)d_in[8];
    const float* bias2 = (const float*)d_in[9];
    float* outp = (float*)d_out;

    const int IN_DIM = 128, H1 = 4, C1 = 64, HC1 = 256, C2 = 128;
    const int N = in_sizes[0] / IN_DIM;
    const int E = in_sizes[1] / 2;
    const int Et = E + N;

    // workspace layout (4-byte units)
    float* ws  = (float*)d_ws;
    float* h1  = ws;                          // N*256
    float* x1  = h1 + (size_t)N * HC1;        // N*256
    float* h2  = x1 + (size_t)N * HC1;        // N*128
    float* as_ = h2 + (size_t)N * C2;         // N*4
    float* ad_ = as_ + (size_t)N * 4;         // N*4
    int* deg    = (int*)(ad_ + (size_t)N * 4);  // N
    int* rowst  = deg + N;                      // N
    int* cursor = rowst + N;                    // N
    int* incl   = cursor + N;                   // N
    int* bsum   = incl + N;                     // 256
    int* col    = bsum + 256;                   // Et

    dim3 blk(256);
    const int nb = (N + 255) / 256;

    // ---- CSR build (shared by both layers) ----
    zero2_kernel<<<dim3(256), blk, 0, stream>>>(deg, cursor, N);
    deg_kernel<<<dim3((Et + 255) / 256), blk, 0, stream>>>(ei, E, N, deg);
    scan1_kernel<<<dim3(nb), blk, 0, stream>>>(deg, incl, bsum, N);
    scan2_kernel<<<dim3(1), blk, 0, stream>>>(bsum, nb);
    scan3_kernel<<<dim3(nb), blk, 0, stream>>>(incl, deg, bsum, rowst, N);
    fill_kernel<<<dim3((Et + 255) / 256), blk, 0, stream>>>(ei, E, N, rowst, cursor, col);

    // ---- layer 1 (H=4, C=64) ----
    {
        dim3 g1((N + 63) / 64, HC1 / 64);
        sgemm_kernel<64, 64, 16, 4, 4><<<g1, blk, 0, stream>>>(feat, W1, h1, N, HC1, IN_DIM);
        attn_coef_kernel<<<dim3((N * H1 + 255) / 256), blk, 0, stream>>>(h1, asrc1, adst1, as_, ad_, N, H1, C1);
        gat_gather_kernel<4, 64, false><<<dim3(N), dim3(256), 0, stream>>>(
            rowst, deg, col, as_, ad_, h1, bias1, nullptr, x1, N);
    }

    // ---- layer 2 (H=1, C=128) ----
    {
        dim3 g2((N + 63) / 64, C2 / 64);
        sgemm_kernel<64, 64, 16, 4, 4><<<g2, blk, 0, stream>>>(x1, W2, h2, N, C2, HC1);
        attn_coef_kernel<<<dim3((N + 255) / 256), blk, 0, stream>>>(h2, asrc2, adst2, as_, ad_, N, 1, C2);
        gat_gather_kernel<1, 128, true><<<dim3(N), dim3(128), 0, stream>>>(
            rowst, deg, col, as_, ad_, h2, bias2, feat, outp, N);
    }
}

// Round 3
// 532.426 us; speedup vs baseline: 9.4334x; 1.2974x over previous
//
#include <hip/hip_runtime.h>
#include <math.h>

#define LRELU(x) ((x) > 0.0f ? (x) : 0.2f * (x))

typedef __attribute__((ext_vector_type(8))) short bf16x8;
typedef __attribute__((ext_vector_type(4))) float floatx4;

__device__ __forceinline__ float bf2f(ushort u) {
    union { unsigned u; float f; } v; v.u = ((unsigned)u) << 16; return v.f;
}
__device__ __forceinline__ ushort f2bf(float f) {
    union { float f; unsigned u; } v; v.f = f;
    unsigned r = (v.u + 0x7FFFu + ((v.u >> 16) & 1u)) >> 16;
    return (ushort)r;
}

// ---------------- fp32 -> bf16 elementwise convert (float4 -> ushort4) ----------------
__global__ __launch_bounds__(256) void cvt_bf16_kernel(
    const float* __restrict__ in, ushort* __restrict__ out, int n4)
{
    int i = blockIdx.x * 256 + threadIdx.x;
    if (i >= n4) return;
    float4 v = ((const float4*)in)[i];
    ushort4 o;
    o.x = f2bf(v.x); o.y = f2bf(v.y); o.z = f2bf(v.z); o.w = f2bf(v.w);
    ((ushort4*)out)[i] = o;
}

// ---------------- pack weight: W[K][Nc] fp32 -> Wt[Nc][K] bf16 ----------------
__global__ __launch_bounds__(256) void pack_w_kernel(
    const float* __restrict__ W, ushort* __restrict__ Wt, int K, int Nc)
{
    int i = blockIdx.x * 256 + threadIdx.x;
    if (i >= K * Nc) return;
    int k = i / Nc, n = i % Nc;
    Wt[(size_t)n * K + k] = f2bf(W[i]);
}

// ---------------- MFMA GEMM: H[M,NT*16] = A[M,K] @ B[K,NT*16] (B packed as [n][k]) ----------------
// block = 4 waves; wave w computes rows [blk*64 + w*16, +16) x all NT*16 cols.
// A-frag layout (16x16x32 bf16): A[m = lane&15][k = (lane>>4)*8 + j]
// B-frag:                        B[n = lane&15][k = (lane>>4)*8 + j]  (hence [n][k] packing)
// C/D layout: col = lane&15, row = (lane>>4)*4 + reg
template <int K, int NT>
__global__ __launch_bounds__(256) void mfma_gemm_kernel(
    const ushort* __restrict__ A, const ushort* __restrict__ Bp,
    ushort* __restrict__ Hout, int M)
{
    const int lane = threadIdx.x & 63;
    const int wave = threadIdx.x >> 6;
    const int quad = lane >> 4;
    const int l16  = lane & 15;
    const int row0 = blockIdx.x * 64 + wave * 16;

    const int arow = min(row0 + l16, M - 1);
    const ushort* ap = A + (size_t)arow * K + quad * 8;

    floatx4 acc[NT];
#pragma unroll
    for (int i = 0; i < NT; ++i) acc[i] = (floatx4){0.f, 0.f, 0.f, 0.f};

#pragma unroll
    for (int k0 = 0; k0 < K; k0 += 32) {
        bf16x8 a = *(const bf16x8*)(ap + k0);
#pragma unroll
        for (int nt = 0; nt < NT; ++nt) {
            const ushort* bp = Bp + (size_t)(nt * 16 + l16) * K + k0 + quad * 8;
            bf16x8 b = *(const bf16x8*)bp;
            acc[nt] = __builtin_amdgcn_mfma_f32_16x16x32_bf16(a, b, acc[nt], 0, 0, 0);
        }
    }

    constexpr int NCOL = NT * 16;
#pragma unroll
    for (int nt = 0; nt < NT; ++nt) {
#pragma unroll
        for (int r = 0; r < 4; ++r) {
            int row = row0 + quad * 4 + r;
            if (row < M) Hout[(size_t)row * NCOL + nt * 16 + l16] = f2bf(acc[nt][r]);
        }
    }
}

// --------- attention coefficients from bf16 h: as[n,h] = <h[n,h,:], att_src[h,:]> ---------
__global__ __launch_bounds__(256) void attn_coef_kernel(
    const ushort* __restrict__ h, const float* __restrict__ att_src,
    const float* __restrict__ att_dst, float* __restrict__ as_, float* __restrict__ ad_,
    int N, int H, int C)
{
    int idx = blockIdx.x * blockDim.x + threadIdx.x;  // n*H + h
    if (idx >= N * H) return;
    int hh = idx % H;
    const ushort* hp = h + (size_t)idx * C;
    const float* asv = att_src + hh * C;
    const float* adv = att_dst + hh * C;
    float s = 0.0f, d = 0.0f;
    for (int c = 0; c < C; c += 4) {
        ushort4 u = *(const ushort4*)(hp + c);
        float f0 = bf2f(u.x), f1 = bf2f(u.y), f2 = bf2f(u.z), f3 = bf2f(u.w);
        s += f0 * asv[c] + f1 * asv[c + 1] + f2 * asv[c + 2] + f3 * asv[c + 3];
        d += f0 * adv[c] + f1 * adv[c + 1] + f2 * adv[c + 2] + f3 * adv[c + 3];
    }
    as_[idx] = s;
    ad_[idx] = d;
}

// ================= CSR build (graph shared by both layers) =================
__global__ __launch_bounds__(256) void zero2_kernel(int* __restrict__ a, int* __restrict__ b, int N)
{
    int i = blockIdx.x * blockDim.x + threadIdx.x;
    int stride = gridDim.x * blockDim.x;
    for (int j = i; j < N; j += stride) { a[j] = 0; b[j] = 0; }
}

__global__ __launch_bounds__(256) void deg_kernel(
    const int* __restrict__ ei, int E, int N, int* __restrict__ deg)
{
    int k = blockIdx.x * blockDim.x + threadIdx.x;
    int Et = E + N;
    if (k >= Et) return;
    int dst = (k < E) ? ei[E + k] : (k - E);
    atomicAdd(&deg[dst], 1);
}

__global__ __launch_bounds__(256) void scan1_kernel(
    const int* __restrict__ deg, int* __restrict__ incl, int* __restrict__ bsum, int N)
{
    __shared__ int s[256];
    int t = threadIdx.x;
    int i = blockIdx.x * 256 + t;
    s[t] = (i < N) ? deg[i] : 0;
    __syncthreads();
    for (int off = 1; off < 256; off <<= 1) {
        int x = (t >= off) ? s[t - off] : 0;
        __syncthreads();
        s[t] += x;
        __syncthreads();
    }
    if (i < N) incl[i] = s[t];
    if (t == 255) bsum[blockIdx.x] = s[255];
}

__global__ __launch_bounds__(256) void scan2_kernel(int* __restrict__ bsum, int nb)
{
    __shared__ int s[256];
    int t = threadIdx.x;
    s[t] = (t < nb) ? bsum[t] : 0;
    __syncthreads();
    for (int off = 1; off < 256; off <<= 1) {
        int x = (t >= off) ? s[t - off] : 0;
        __syncthreads();
        s[t] += x;
        __syncthreads();
    }
    if (t < nb) bsum[t] = s[t];
}

__global__ __launch_bounds__(256) void scan3_kernel(
    const int* __restrict__ incl, const int* __restrict__ deg,
    const int* __restrict__ bsum, int* __restrict__ row_start, int N)
{
    int i = blockIdx.x * 256 + threadIdx.x;
    if (i >= N) return;
    int off = (blockIdx.x > 0) ? bsum[blockIdx.x - 1] : 0;
    row_start[i] = off + incl[i] - deg[i];
}

__global__ __launch_bounds__(256) void fill_kernel(
    const int* __restrict__ ei, int E, int N,
    const int* __restrict__ row_start, int* __restrict__ cursor, int* __restrict__ col)
{
    int k = blockIdx.x * blockDim.x + threadIdx.x;
    int Et = E + N;
    if (k >= Et) return;
    int src, dst;
    if (k < E) { src = ei[k]; dst = ei[E + k]; }
    else       { src = dst = k - E; }
    int pos = row_start[dst] + atomicAdd(&cursor[dst], 1);
    col[pos] = src;
}

// ================= fused per-dst gather: softmax + aggregation + epilogue =================
// one block per dst node, H*C threads; thread t owns output channel t (head t/C)
template <int H, int C, bool RES, bool OUTBF>
__global__ __launch_bounds__(H * C) void gat_gather_kernel(
    const int* __restrict__ row_start, const int* __restrict__ deg,
    const int* __restrict__ col,
    const float* __restrict__ as_, const float* __restrict__ ad_,
    const ushort* __restrict__ h, const float* __restrict__ bias,
    const float* __restrict__ resid, void* __restrict__ outv, int N)
{
    constexpr int HC = H * C;
    constexpr int JT = HC / H;
    constexpr int TILE = 32;
    __shared__ float red[HC];
    __shared__ float smax[H], sden[H], sad[H];
    __shared__ float salpha[TILE * H];
    __shared__ int   ssrc[TILE];

    const int n = blockIdx.x;
    const int t = threadIdx.x;
    const int start = row_start[n];
    const int dg = deg[n];

    if (t < H) sad[t] = ad_[n * H + t];
    __syncthreads();

    const int hh = t % H;
    const int j0 = t / H;
    const float adv = sad[hh];

    // ---- pass 1: per-head max of leaky_relu(as[src]+ad[n]) ----
    float lmax = -1e30f;
    for (int j = j0; j < dg; j += JT) {
        int src = col[start + j];
        float e = as_[src * H + hh] + adv;
        e = LRELU(e);
        lmax = fmaxf(lmax, e);
    }
    red[t] = lmax;
    __syncthreads();
    for (int s = HC / 2; s >= H; s >>= 1) {
        if (t < s) red[t] = fmaxf(red[t], red[t + s]);
        __syncthreads();
    }
    if (t < H) smax[t] = red[t];
    __syncthreads();

    // ---- pass 2: per-head sum of exp ----
    const float mh = smax[hh];
    float lsum = 0.0f;
    for (int j = j0; j < dg; j += JT) {
        int src = col[start + j];
        float e = as_[src * H + hh] + adv;
        e = LRELU(e);
        lsum += __expf(e - mh);
    }
    red[t] = lsum;
    __syncthreads();
    for (int s = HC / 2; s >= H; s >>= 1) {
        if (t < s) red[t] += red[t + s];
        __syncthreads();
    }
    if (t < H) sden[t] = 1.0f / red[t];
    __syncthreads();

    // ---- pass 3: aggregate alpha * h[src] in edge tiles ----
    const int ch_head = t / C;
    float acc = 0.0f;
    for (int base = 0; base < dg; base += TILE) {
        int cnt = min(TILE, dg - base);
        for (int idx = t; idx < cnt * H; idx += HC) {
            int j = idx / H, h2 = idx % H;
            int src = col[start + base + j];
            if (h2 == 0) ssrc[j] = src;
            float e = as_[src * H + h2] + sad[h2];
            e = LRELU(e);
            salpha[idx] = __expf(e - smax[h2]) * sden[h2];
        }
        __syncthreads();
        for (int j = 0; j < cnt; ++j)
            acc += salpha[j * H + ch_head] * bf2f(h[(size_t)ssrc[j] * HC + t]);
        __syncthreads();
    }

    float v = acc + bias[t];
    v = LRELU(v);
    if (RES) v += resid[(size_t)n * HC + t];
    if (OUTBF) ((ushort*)outv)[(size_t)n * HC + t] = f2bf(v);
    else       ((float*)outv)[(size_t)n * HC + t] = v;
}

extern "C" void kernel_launch(void* const* d_in, const int* in_sizes, int n_in,
                              void* d_out, int out_size, void* d_ws, size_t ws_size,
                              hipStream_t stream)
{
    const float* feat = (const float*)d_in[0];
    const int*   ei   = (const int*)d_in[1];
    const float* W1   = (const float*)d_in[2];
    const float* asrc1 = (const float*)d_in[3];
    const float* adst1 = (const float*)d_in[4];
    const float* bias1 = (const float*)d_in[5];
    const float* W2    = (const float*)d_in[6];
    const float* asrc2 = (const float*)d_in[7];
    const float* adst2 = (const float*)d_in[8];
    const float* bias2 = (const float*)d_in[9];
    float* outp = (float*)d_out;

    const int IN_DIM = 128, H1 = 4, C1 = 64, HC1 = 256, C2 = 128;
    const int N = in_sizes[0] / IN_DIM;
    const int E = in_sizes[1] / 2;
    const int Et = E + N;

    // workspace layout (bytes)
    char* w = (char*)d_ws;
    ushort* h1b   = (ushort*)w; w += (size_t)N * HC1 * 2;
    ushort* x1b   = (ushort*)w; w += (size_t)N * HC1 * 2;
    ushort* h2b   = (ushort*)w; w += (size_t)N * C2 * 2;
    ushort* featb = (ushort*)w; w += (size_t)N * IN_DIM * 2;
    ushort* W1T   = (ushort*)w; w += (size_t)IN_DIM * HC1 * 2;
    ushort* W2T   = (ushort*)w; w += (size_t)HC1 * C2 * 2;
    float* as_    = (float*)w;  w += (size_t)N * H1 * 4;
    float* ad_    = (float*)w;  w += (size_t)N * H1 * 4;
    int* deg      = (int*)w;    w += (size_t)N * 4;
    int* rowst    = (int*)w;    w += (size_t)N * 4;
    int* cursor   = (int*)w;    w += (size_t)N * 4;
    int* incl     = (int*)w;    w += (size_t)N * 4;
    int* bsum     = (int*)w;    w += 256 * 4;
    int* col      = (int*)w;    w += (size_t)Et * 4;

    dim3 blk(256);
    const int nb = (N + 255) / 256;
    const int mg = (N + 63) / 64;   // mfma gemm grid

    // ---- input conversions / weight packing ----
    cvt_bf16_kernel<<<dim3((N * IN_DIM / 4 + 255) / 256), blk, 0, stream>>>(feat, featb, N * IN_DIM / 4);
    pack_w_kernel<<<dim3((IN_DIM * HC1 + 255) / 256), blk, 0, stream>>>(W1, W1T, IN_DIM, HC1);
    pack_w_kernel<<<dim3((HC1 * C2 + 255) / 256), blk, 0, stream>>>(W2, W2T, HC1, C2);

    // ---- CSR build ----
    zero2_kernel<<<dim3(256), blk, 0, stream>>>(deg, cursor, N);
    deg_kernel<<<dim3((Et + 255) / 256), blk, 0, stream>>>(ei, E, N, deg);
    scan1_kernel<<<dim3(nb), blk, 0, stream>>>(deg, incl, bsum, N);
    scan2_kernel<<<dim3(1), blk, 0, stream>>>(bsum, nb);
    scan3_kernel<<<dim3(nb), blk, 0, stream>>>(incl, deg, bsum, rowst, N);
    fill_kernel<<<dim3((Et + 255) / 256), blk, 0, stream>>>(ei, E, N, rowst, cursor, col);

    // ---- layer 1 (H=4, C=64) ----
    mfma_gemm_kernel<128, 16><<<dim3(mg), blk, 0, stream>>>(featb, W1T, h1b, N);
    attn_coef_kernel<<<dim3((N * H1 + 255) / 256), blk, 0, stream>>>(h1b, asrc1, adst1, as_, ad_, N, H1, C1);
    gat_gather_kernel<4, 64, false, true><<<dim3(N), dim3(256), 0, stream>>>(
        rowst, deg, col, as_, ad_, h1b, bias1, nullptr, x1b, N);

    // ---- layer 2 (H=1, C=128) ----
    mfma_gemm_kernel<256, 8><<<dim3(mg), blk, 0, stream>>>(x1b, W2T, h2b, N);
    attn_coef_kernel<<<dim3((N + 255) / 256), blk, 0, stream>>>(h2b, asrc2, adst2, as_, ad_, N, 1, C2);
    gat_gather_kernel<1, 128, true, false><<<dim3(N), dim3(128), 0, stream>>>(
        rowst, deg, col, as_, ad_, h2b, bias2, feat, outp, N);
}